// Round 1
// baseline (964.187 us; speedup 1.0000x reference)
//
#include <hip/hip_runtime.h>
#include <hip/hip_bf16.h>

typedef __bf16 bf16;
typedef __bf16 bf16x8 __attribute__((ext_vector_type(8)));
typedef float f32x4 __attribute__((ext_vector_type(4)));

#define DEVINL __device__ __forceinline__

constexpr int L_ = 2, R_ = 4, S_ = 1024, H_ = 1024;
constexpr int NH_ = 16, NKV_ = 8, DH_ = 128;
constexpr int FF_ = 3072;
constexpr int T_ = R_ * S_;  // 4096 tokens

// ---------------------------------------------------------------- RoPE tables
__global__ void rope_tables_kernel(float* __restrict__ cosb, float* __restrict__ sinb) {
    int s = blockIdx.x;           // position 0..S-1
    int i = threadIdx.x;          // 0..63
    float inv = __expf(-(float)i * (1.0f / 64.0f) * 13.815510557964274f);  // 1e6^(-i/64)
    float f = (float)s * inv;
    cosb[s * 64 + i] = cosf(f);
    sinb[s * 64 + i] = sinf(f);
}

// ---------------------------------------------------------------- RMSNorm
template <bool OUT_BF16>
__global__ __launch_bounds__(256) void rmsnorm_kernel(const float* __restrict__ x,
                                                      const float* __restrict__ w,
                                                      void* __restrict__ out) {
    int row = blockIdx.x;
    const float* xr = x + (size_t)row * H_;
    int t = threadIdx.x;
    float v[4];
    float ss = 0.f;
#pragma unroll
    for (int j = 0; j < 4; ++j) {
        v[j] = xr[t + 256 * j];
        ss += v[j] * v[j];
    }
#pragma unroll
    for (int off = 32; off; off >>= 1) ss += __shfl_xor(ss, off);
    __shared__ float part[4];
    if ((t & 63) == 0) part[t >> 6] = ss;
    __syncthreads();
    ss = part[0] + part[1] + part[2] + part[3];
    float r = rsqrtf(ss * (1.0f / (float)H_) + 1e-6f);
#pragma unroll
    for (int j = 0; j < 4; ++j) {
        int c = t + 256 * j;
        float o = v[j] * r * w[c];
        if constexpr (OUT_BF16)
            ((bf16*)out)[(size_t)row * H_ + c] = (bf16)o;
        else
            ((float*)out)[(size_t)row * H_ + c] = o;
    }
}

// ---------------------------------------------------------------- transpose+cast f32[Rk][Cn] -> bf16[Cn][Rk]
__global__ __launch_bounds__(256) void transpose_cast_kernel(const float* __restrict__ in,
                                                             bf16* __restrict__ out,
                                                             int Rk, int Cn) {
    __shared__ float tile[32][33];
    int c0 = blockIdx.x * 32, r0 = blockIdx.y * 32;
    int t = threadIdx.x;
    int tc = t & 31, tr = t >> 5;  // 8 rows per iter
#pragma unroll
    for (int i = 0; i < 4; ++i) {
        int r = tr + i * 8;
        tile[r][tc] = in[(size_t)(r0 + r) * Cn + c0 + tc];
    }
    __syncthreads();
#pragma unroll
    for (int i = 0; i < 4; ++i) {
        int r = tr + i * 8;  // output row = c0 + r
        out[(size_t)(c0 + r) * Rk + r0 + tc] = (bf16)tile[tc][r];
    }
}

// ---------------------------------------------------------------- GEMM  C[M,N] = A[M,K] * Bt[N,K]^T
// EPI: 0 = f32 out, 1 = bf16 out, 2 = bf16 silu, 3 = bf16 (val * mul[idx]), 4 = f32 (val + res[idx])
template <int EPI>
__global__ __launch_bounds__(256) void gemm_kernel(const bf16* __restrict__ A,
                                                   const bf16* __restrict__ Bt,
                                                   void* __restrict__ out,
                                                   const float* __restrict__ res,
                                                   const bf16* __restrict__ mul,
                                                   int M, int N, int K) {
    __shared__ bf16 Al[128][48];
    __shared__ bf16 Bl[128][48];
    int bm = blockIdx.y * 128, bn = blockIdx.x * 128;
    int t = threadIdx.x;
    int lane = t & 63, w = t >> 6;
    int wr = w >> 1, wc = w & 1;
    f32x4 acc[4][4] = {};

    int lr = t >> 2;         // 0..63
    int lk = (t & 3) * 8;    // 0,8,16,24
    const bf16* Ap = A + (size_t)(bm + lr) * K + lk;
    const bf16* Bp = Bt + (size_t)(bn + lr) * K + lk;

    int kl = (lane >> 4) * 8;
    int rm = wr * 64 + (lane & 15);
    int rn = wc * 64 + (lane & 15);

    for (int k0 = 0; k0 < K; k0 += 32) {
        *(bf16x8*)(&Al[lr][lk]) = *(const bf16x8*)(Ap);
        *(bf16x8*)(&Al[lr + 64][lk]) = *(const bf16x8*)(Ap + (size_t)64 * K);
        *(bf16x8*)(&Bl[lr][lk]) = *(const bf16x8*)(Bp);
        *(bf16x8*)(&Bl[lr + 64][lk]) = *(const bf16x8*)(Bp + (size_t)64 * K);
        Ap += 32;
        Bp += 32;
        __syncthreads();
        bf16x8 af[4], bfv[4];
#pragma unroll
        for (int m = 0; m < 4; ++m) af[m] = *(const bf16x8*)(&Al[rm + m * 16][kl]);
#pragma unroll
        for (int n = 0; n < 4; ++n) bfv[n] = *(const bf16x8*)(&Bl[rn + n * 16][kl]);
#pragma unroll
        for (int m = 0; m < 4; ++m)
#pragma unroll
            for (int n = 0; n < 4; ++n)
                acc[m][n] = __builtin_amdgcn_mfma_f32_16x16x32_bf16(af[m], bfv[n], acc[m][n], 0, 0, 0);
        __syncthreads();
    }

    int rbase = bm + wr * 64 + ((lane >> 4) << 2);
    int cbase = bn + wc * 64 + (lane & 15);
#pragma unroll
    for (int m = 0; m < 4; ++m) {
#pragma unroll
        for (int n = 0; n < 4; ++n) {
#pragma unroll
            for (int g = 0; g < 4; ++g) {
                int row = rbase + m * 16 + g;
                int col = cbase + n * 16;
                size_t idx = (size_t)row * N + col;
                float val = acc[m][n][g];
                if constexpr (EPI == 0) {
                    ((float*)out)[idx] = val;
                } else if constexpr (EPI == 1) {
                    ((bf16*)out)[idx] = (bf16)val;
                } else if constexpr (EPI == 2) {
                    ((bf16*)out)[idx] = (bf16)(val / (1.0f + __expf(-val)));
                } else if constexpr (EPI == 3) {
                    ((bf16*)out)[idx] = (bf16)(val * (float)mul[idx]);
                } else {
                    ((float*)out)[idx] = val + res[idx];
                }
            }
        }
    }
}

// ---------------------------------------------------------------- per-head RMS + RoPE for q/k, relayout v
DEVINL void head_norm_rope(const bf16* __restrict__ src, const float* __restrict__ w,
                           const float* __restrict__ cosb, const float* __restrict__ sinb,
                           int s, int ln, bf16* __restrict__ dst) {
    float x0 = (float)src[ln], x1 = (float)src[ln + 32];
    float x2 = (float)src[ln + 64], x3 = (float)src[ln + 96];
    float ss = x0 * x0 + x1 * x1 + x2 * x2 + x3 * x3;
#pragma unroll
    for (int off = 16; off; off >>= 1) ss += __shfl_xor(ss, off);
    float rr = rsqrtf(ss * (1.0f / 128.0f) + 1e-6f);
    float n0 = x0 * rr * w[ln], n1 = x1 * rr * w[ln + 32];
    float n2 = x2 * rr * w[ln + 64], n3 = x3 * rr * w[ln + 96];
    float c0 = cosb[s * 64 + ln], c1 = cosb[s * 64 + ln + 32];
    float s0 = sinb[s * 64 + ln], s1 = sinb[s * 64 + ln + 32];
    dst[ln] = (bf16)(n0 * c0 - n2 * s0);
    dst[ln + 32] = (bf16)(n1 * c1 - n3 * s1);
    dst[ln + 64] = (bf16)(n2 * c0 + n0 * s0);
    dst[ln + 96] = (bf16)(n3 * c1 + n1 * s1);
}

__global__ __launch_bounds__(256) void qkv_post_kernel(const bf16* __restrict__ qkv,
                                                       const float* __restrict__ qw,
                                                       const float* __restrict__ kw,
                                                       const float* __restrict__ cosb,
                                                       const float* __restrict__ sinb,
                                                       bf16* __restrict__ qo,
                                                       bf16* __restrict__ ko,
                                                       bf16* __restrict__ vo) {
    int tok = blockIdx.x;
    int r = tok >> 10, s = tok & 1023;
    int t = threadIdx.x;
    int g = t >> 5;   // group 0..7 (32 lanes each)
    int ln = t & 31;
    const bf16* row = qkv + (size_t)tok * 4096;
#pragma unroll
    for (int hh = 0; hh < 2; ++hh) {
        int h = g + hh * 8;
        head_norm_rope(row + h * 128, qw, cosb, sinb, s, ln,
                       qo + ((size_t)(r * NH_ + h) * S_ + s) * 128);
    }
    head_norm_rope(row + 2048 + g * 128, kw, cosb, sinb, s, ln,
                   ko + ((size_t)(r * NKV_ + g) * S_ + s) * 128);
#pragma unroll
    for (int j = 0; j < 4; ++j) {
        int d = t + j * 256;
        int vh = d >> 7, dd = d & 127;
        vo[((size_t)(r * NKV_ + vh) * S_ + s) * 128 + dd] = row[3072 + d];
    }
}

// ---------------------------------------------------------------- flash attention (causal, GQA)
// grid: (S/64, NH, R), block 256 (4 waves, 16 q-rows each)
__global__ __launch_bounds__(256) void flash_kernel(const bf16* __restrict__ q,
                                                    const bf16* __restrict__ k,
                                                    const bf16* __restrict__ v,
                                                    bf16* __restrict__ out) {
    __shared__ bf16 Kl[32][144];   // K tile, padded
    __shared__ bf16 Vt[128][48];   // V tile transposed [d][kv]
    __shared__ bf16 Pl[4][16][48]; // per-wave P tile
    int qt = blockIdx.x, h = blockIdx.y, r = blockIdx.z;
    int kvh = h >> 1;
    int t = threadIdx.x, lane = t & 63, w = t >> 6;
    int qbase = qt * 64 + w * 16;

    int arow = lane & 15, koff = (lane >> 4) * 8;
    const bf16* qp = q + ((size_t)(r * NH_ + h) * S_ + qbase) * 128;
    bf16x8 qf[4];
#pragma unroll
    for (int kc = 0; kc < 4; ++kc)
        qf[kc] = *(const bf16x8*)(qp + (size_t)arow * 128 + kc * 32 + koff);

    f32x4 ao[8] = {};
    float mrow[4], lrow[4];
#pragma unroll
    for (int g = 0; g < 4; ++g) { mrow[g] = -1e30f; lrow[g] = 0.f; }

    const bf16* kp = k + (size_t)(r * NKV_ + kvh) * S_ * 128;
    const bf16* vp = v + (size_t)(r * NKV_ + kvh) * S_ * 128;

    int krow = t >> 3, d0 = (t & 7) * 16;
    int nk = qt * 64 + 64;
    const float scale = 0.08838834764831845f;

    for (int kv0 = 0; kv0 < nk; kv0 += 32) {
        __syncthreads();
        // stage K tile
        *(bf16x8*)(&Kl[krow][d0]) = *(const bf16x8*)(kp + (size_t)(kv0 + krow) * 128 + d0);
        *(bf16x8*)(&Kl[krow][d0 + 8]) = *(const bf16x8*)(kp + (size_t)(kv0 + krow) * 128 + d0 + 8);
        // stage V tile transposed
        bf16x8 vv0 = *(const bf16x8*)(vp + (size_t)(kv0 + krow) * 128 + d0);
        bf16x8 vv1 = *(const bf16x8*)(vp + (size_t)(kv0 + krow) * 128 + d0 + 8);
#pragma unroll
        for (int i = 0; i < 8; ++i) Vt[d0 + i][krow] = vv0[i];
#pragma unroll
        for (int i = 0; i < 8; ++i) Vt[d0 + 8 + i][krow] = vv1[i];
        __syncthreads();

        // scores = Q * K^T  (16 x 32)
        f32x4 sc[2];
#pragma unroll
        for (int n = 0; n < 2; ++n) {
            sc[n] = (f32x4){0.f, 0.f, 0.f, 0.f};
#pragma unroll
            for (int kc = 0; kc < 4; ++kc) {
                bf16x8 kf = *(const bf16x8*)(&Kl[n * 16 + arow][kc * 32 + koff]);
                sc[n] = __builtin_amdgcn_mfma_f32_16x16x32_bf16(qf[kc], kf, sc[n], 0, 0, 0);
            }
        }
        float pm[2][4];
#pragma unroll
        for (int n = 0; n < 2; ++n)
#pragma unroll
            for (int g = 0; g < 4; ++g) {
                float sval = sc[n][g] * scale;
                int kg = kv0 + n * 16 + (lane & 15);
                int rq = qbase + ((lane >> 4) << 2) + g;
                if (kg > rq) sval = -1e30f;
                pm[n][g] = sval;
            }
        float mx[4], sf[4], rs[4];
#pragma unroll
        for (int g = 0; g < 4; ++g) mx[g] = fmaxf(pm[0][g], pm[1][g]);
#pragma unroll
        for (int off = 8; off; off >>= 1)
#pragma unroll
            for (int g = 0; g < 4; ++g) mx[g] = fmaxf(mx[g], __shfl_xor(mx[g], off));
#pragma unroll
        for (int g = 0; g < 4; ++g) {
            float mnew = fmaxf(mrow[g], mx[g]);
            sf[g] = __expf(mrow[g] - mnew);
            mrow[g] = mnew;
        }
#pragma unroll
        for (int n = 0; n < 2; ++n)
#pragma unroll
            for (int g = 0; g < 4; ++g) pm[n][g] = __expf(pm[n][g] - mrow[g]);
#pragma unroll
        for (int g = 0; g < 4; ++g) rs[g] = pm[0][g] + pm[1][g];
#pragma unroll
        for (int off = 8; off; off >>= 1)
#pragma unroll
            for (int g = 0; g < 4; ++g) rs[g] += __shfl_xor(rs[g], off);
#pragma unroll
        for (int g = 0; g < 4; ++g) lrow[g] = lrow[g] * sf[g] + rs[g];
#pragma unroll
        for (int c = 0; c < 8; ++c)
#pragma unroll
            for (int g = 0; g < 4; ++g) ao[c][g] *= sf[g];
        // P -> LDS (wave-local), then PV
#pragma unroll
        for (int n = 0; n < 2; ++n)
#pragma unroll
            for (int g = 0; g < 4; ++g)
                Pl[w][((lane >> 4) << 2) + g][n * 16 + (lane & 15)] = (bf16)pm[n][g];
        bf16x8 pf = *(const bf16x8*)(&Pl[w][arow][koff]);
#pragma unroll
        for (int c = 0; c < 8; ++c) {
            bf16x8 vf = *(const bf16x8*)(&Vt[c * 16 + arow][koff]);
            ao[c] = __builtin_amdgcn_mfma_f32_16x16x32_bf16(pf, vf, ao[c], 0, 0, 0);
        }
    }
    // epilogue: normalize and store [r*S+row][h*128+col]
#pragma unroll
    for (int c = 0; c < 8; ++c)
#pragma unroll
        for (int g = 0; g < 4; ++g) {
            int rq = qbase + ((lane >> 4) << 2) + g;
            out[(size_t)(r * S_ + rq) * 2048 + h * 128 + c * 16 + (lane & 15)] =
                (bf16)(ao[c][g] / lrow[g]);
        }
}

// ---------------------------------------------------------------- host
extern "C" void kernel_launch(void* const* d_in, const int* in_sizes, int n_in,
                              void* d_out, int out_size, void* d_ws, size_t ws_size,
                              hipStream_t stream) {
    const float* hidden = (const float*)d_in[0];
    const float* Wq = (const float*)d_in[1];
    const float* Wk = (const float*)d_in[2];
    const float* Wv = (const float*)d_in[3];
    const float* Wo = (const float*)d_in[4];
    const float* qnw = (const float*)d_in[5];
    const float* knw = (const float*)d_in[6];
    const float* ln1 = (const float*)d_in[7];
    const float* ln2 = (const float*)d_in[8];
    const float* Wg = (const float*)d_in[9];
    const float* Wu = (const float*)d_in[10];
    const float* Wd = (const float*)d_in[11];
    const float* fnw = (const float*)d_in[12];
    float* out = (float*)d_out;

    char* ws = (char*)d_ws;
    size_t off = 0;
    auto alloc = [&](size_t bytes) -> char* {
        char* p = ws + off;
        off += (bytes + 255) & ~(size_t)255;
        return p;
    };
    float* cosb = (float*)alloc((size_t)S_ * 64 * 4);
    float* sinb = (float*)alloc((size_t)S_ * 64 * 4);
    float* x_ws = (float*)alloc((size_t)T_ * H_ * 4);
    bf16* hbuf = (bf16*)alloc((size_t)T_ * H_ * 2);
    bf16* qkv = (bf16*)alloc((size_t)T_ * 4096 * 2);  // shared region: qkv then act
    bf16* act = qkv;
    bf16* qb = (bf16*)alloc((size_t)R_ * NH_ * S_ * 128 * 2);
    bf16* kb = (bf16*)alloc((size_t)R_ * NKV_ * S_ * 128 * 2);
    bf16* vb = (bf16*)alloc((size_t)R_ * NKV_ * S_ * 128 * 2);
    bf16* attn = (bf16*)alloc((size_t)T_ * 2048 * 2);
    bf16* wqkv_t = (bf16*)alloc((size_t)4096 * 1024 * 2);
    bf16* wo_t = (bf16*)alloc((size_t)1024 * 2048 * 2);
    bf16* wg_t = (bf16*)alloc((size_t)3072 * 1024 * 2);
    bf16* wu_t = (bf16*)alloc((size_t)3072 * 1024 * 2);
    bf16* wd_t = (bf16*)alloc((size_t)1024 * 3072 * 2);

    rope_tables_kernel<<<S_, 64, 0, stream>>>(cosb, sinb);

    const float* xin = hidden;
    for (int l = 0; l < L_; ++l) {
        // weight transpose + cast
        transpose_cast_kernel<<<dim3(2048 / 32, 1024 / 32), 256, 0, stream>>>(
            Wq + (size_t)l * H_ * 2048, wqkv_t, 1024, 2048);
        transpose_cast_kernel<<<dim3(1024 / 32, 1024 / 32), 256, 0, stream>>>(
            Wk + (size_t)l * H_ * 1024, wqkv_t + (size_t)2048 * 1024, 1024, 1024);
        transpose_cast_kernel<<<dim3(1024 / 32, 1024 / 32), 256, 0, stream>>>(
            Wv + (size_t)l * H_ * 1024, wqkv_t + (size_t)3072 * 1024, 1024, 1024);
        transpose_cast_kernel<<<dim3(1024 / 32, 2048 / 32), 256, 0, stream>>>(
            Wo + (size_t)l * 2048 * 1024, wo_t, 2048, 1024);
        transpose_cast_kernel<<<dim3(3072 / 32, 1024 / 32), 256, 0, stream>>>(
            Wg + (size_t)l * H_ * 3072, wg_t, 1024, 3072);
        transpose_cast_kernel<<<dim3(3072 / 32, 1024 / 32), 256, 0, stream>>>(
            Wu + (size_t)l * H_ * 3072, wu_t, 1024, 3072);
        transpose_cast_kernel<<<dim3(1024 / 32, 3072 / 32), 256, 0, stream>>>(
            Wd + (size_t)l * 3072 * 1024, wd_t, 3072, 1024);

        // attention block
        rmsnorm_kernel<true><<<T_, 256, 0, stream>>>(xin, ln1 + (size_t)l * H_, hbuf);
        gemm_kernel<1><<<dim3(32, 32), 256, 0, stream>>>(hbuf, wqkv_t, qkv, nullptr, nullptr,
                                                         4096, 4096, 1024);
        qkv_post_kernel<<<T_, 256, 0, stream>>>(qkv, qnw + (size_t)l * 128, knw + (size_t)l * 128,
                                                cosb, sinb, qb, kb, vb);
        flash_kernel<<<dim3(16, 16, 4), 256, 0, stream>>>(qb, kb, vb, attn);
        gemm_kernel<4><<<dim3(8, 32), 256, 0, stream>>>(attn, wo_t, x_ws, xin, nullptr,
                                                        4096, 1024, 2048);
        // MLP block
        rmsnorm_kernel<true><<<T_, 256, 0, stream>>>(x_ws, ln2 + (size_t)l * H_, hbuf);
        gemm_kernel<2><<<dim3(24, 32), 256, 0, stream>>>(hbuf, wg_t, act, nullptr, nullptr,
                                                         4096, 3072, 1024);
        gemm_kernel<3><<<dim3(24, 32), 256, 0, stream>>>(hbuf, wu_t, act, nullptr, act,
                                                         4096, 3072, 1024);
        gemm_kernel<4><<<dim3(8, 32), 256, 0, stream>>>(act, wd_t, x_ws, x_ws, nullptr,
                                                        4096, 1024, 3072);
        xin = x_ws;
    }
    rmsnorm_kernel<false><<<T_, 256, 0, stream>>>(x_ws, fnw, out);
}